// Round 13
// baseline (5755.928 us; speedup 1.0000x reference)
//
#include <hip/hip_runtime.h>
#include <hip/hip_bf16.h>
#include <math.h>

// Problem constants
#define B_     32
#define S_     2048
#define E_     300
#define H_     256
#define STEPS_ 24
#define BS_    (B_ * S_)      // 65536
#define NPACK  1280           // 5 gates * 256
#define KSL    16             // 512/32 k-slabs (h part)
#define KSL2   10             // 320/32 k-slabs (x part)
#define COPYB  1024           // copy blocks folded into step dispatch

typedef __bf16 bf16x8 __attribute__((ext_vector_type(8)));
typedef float  f32x4  __attribute__((ext_vector_type(4)));

__device__ __forceinline__ float sigm(float x) {
    return 1.0f / (1.0f + __expf(-x));
}
__device__ __forceinline__ float fast_tanh(float x) {
    return 2.0f * sigm(2.0f * x) - 1.0f;
}
__device__ __forceinline__ float bf16bits2f(unsigned short u) {
    return __uint_as_float(((unsigned)u) << 16);
}
// Async global->LDS, 16B/lane. LDS dest = wave-uniform base + lane*16;
// global src is per-lane. (m03/m97/m104 semantics.)
__device__ __forceinline__ void gload_lds16(const void* g, void* l) {
    __builtin_amdgcn_global_load_lds(
        (const __attribute__((address_space(1))) void*)g,
        (__attribute__((address_space(3))) void*)l, 16, 0, 0);
}

// ---------------------------------------------------------------------------
// Pack step-GEMM B (h part): Bp[ks][p][kin], p = w*80 + g*16 + c_lo.
// k<256 -> U_*_l[k], k>=256 -> U_*_r[k-256]. Gates: 0=i,1=o,2=u,3=f_l,4=f_r.
// ---------------------------------------------------------------------------
__global__ __launch_bounds__(256) void pack_B_kernel(
    const float* __restrict__ U_iou_l, const float* __restrict__ U_iou_r,
    const float* __restrict__ U_f_ll,  const float* __restrict__ U_f_lr,
    const float* __restrict__ U_f_rl,  const float* __restrict__ U_f_rr,
    __hip_bfloat16* __restrict__ Bp)
{
    const int idx = blockIdx.x * 256 + threadIdx.x;      // 16*1280*32 = 655360
    if (idx >= KSL * NPACK * 32) return;
    const int ks = idx / (NPACK * 32);
    const int rem = idx - ks * (NPACK * 32);
    const int p = rem >> 5;
    const int kin = rem & 31;
    const int k = ks * 32 + kin;
    const int w = p / 80;
    const int rg = p - w * 80;
    const int g = rg >> 4;
    const int c = w * 16 + (rg & 15);
    float v;
    if (g < 3) {
        const int col = g * 256 + c;
        v = (k < 256) ? U_iou_l[k * 768 + col] : U_iou_r[(k - 256) * 768 + col];
    } else if (g == 3) {
        v = (k < 256) ? U_f_ll[k * 256 + c] : U_f_lr[(k - 256) * 256 + c];
    } else {
        v = (k < 256) ? U_f_rl[k * 256 + c] : U_f_rr[(k - 256) * 256 + c];
    }
    Bp[idx] = __float2bfloat16(v);
}

// ---------------------------------------------------------------------------
// Pack step-GEMM B (x part): B2[ks2][p][kin] same 5-gate layout; k=ks2*32+kin
// in [0,320). g<3 -> W_iou[k][g*256+c]; g in {3,4} -> W_f[k][c] (duplicated).
// k>=300 zero-padded.
// ---------------------------------------------------------------------------
__global__ __launch_bounds__(256) void pack_B2_kernel(
    const float* __restrict__ W_iou, const float* __restrict__ W_f,
    __hip_bfloat16* __restrict__ B2)
{
    const int idx = blockIdx.x * 256 + threadIdx.x;      // 10*1280*32 = 409600
    if (idx >= KSL2 * NPACK * 32) return;
    const int ks = idx / (NPACK * 32);
    const int rem = idx - ks * (NPACK * 32);
    const int p = rem >> 5;
    const int kin = rem & 31;
    const int k = ks * 32 + kin;
    const int w = p / 80;
    const int rg = p - w * 80;
    const int g = rg >> 4;
    const int c = w * 16 + (rg & 15);
    float v = 0.f;
    if (k < E_) v = (g < 3) ? W_iou[k * 768 + g * 256 + c] : W_f[k * 256 + c];
    B2[idx] = __float2bfloat16(v);
}

// ---------------------------------------------------------------------------
// Input fp32 [BS][300] -> bf16 [BS][512] (zeros past 300)
// ---------------------------------------------------------------------------
__global__ __launch_bounds__(256) void inpcvt_kernel(
    const float* __restrict__ in, __hip_bfloat16* __restrict__ out)
{
    const int idx = blockIdx.x * 256 + threadIdx.x;      // BS*64
    const int row = idx >> 6;
    const int c0 = (idx & 63) * 8;
    union { __hip_bfloat16 h[8]; uint4 u; } o;
#pragma unroll
    for (int j = 0; j < 8; ++j) {
        const int c = c0 + j;
        o.h[j] = (c < E_) ? __float2bfloat16(in[(size_t)row * E_ + c])
                          : __float2bfloat16(0.f);
    }
    *(uint4*)(out + (size_t)row * 512 + c0) = o.u;
}

// ---------------------------------------------------------------------------
// Winner: winner[t][b][d] = max s with tree_ids[b][t][s]==d (last-wins scatter)
// ---------------------------------------------------------------------------
__global__ __launch_bounds__(256) void winner_kernel(
    const int* __restrict__ tree_ids, int* __restrict__ winner)
{
    const int idx = blockIdx.x * 256 + threadIdx.x;
    if (idx >= B_ * STEPS_ * S_) return;
    const int b = idx / (STEPS_ * S_);
    const int rem = idx - b * (STEPS_ * S_);
    const int t = rem / S_;
    const int s = rem - t * S_;
    const int d = tree_ids[idx];
    if ((unsigned)d < (unsigned)S_)
        atomicMax(&winner[(size_t)t * BS_ + b * S_ + d], s);
}

// ---------------------------------------------------------------------------
// Compaction: per (t,b), ordered list of active (s,d) pairs (d!=0, winner>=0),
// packed as (s<<11)|d. compact[tb][k], count[tb]. One block per (t,b).
// ---------------------------------------------------------------------------
__global__ __launch_bounds__(256) void compact_kernel(
    const int* __restrict__ winner, int* __restrict__ compact,
    int* __restrict__ count)
{
    const int tb = blockIdx.x;               // t*32 + b ; winner row = tb*S_
    const int tid = threadIdx.x;
    const int* w = winner + (size_t)tb * S_;
    int* cmp = compact + (size_t)tb * S_;
    __shared__ int scan_[256];
    __shared__ int base_;
    if (tid == 0) base_ = 0;
    __syncthreads();
    for (int chunk = 0; chunk < S_ / 256; ++chunk) {
        const int d = chunk * 256 + tid;
        const int s = w[d];
        const int p = (d != 0 && s >= 0) ? 1 : 0;
        int v = p;
        scan_[tid] = v;
        __syncthreads();
        for (int off = 1; off < 256; off <<= 1) {
            const int add = (tid >= off) ? scan_[tid - off] : 0;
            __syncthreads();
            v += add;
            scan_[tid] = v;
            __syncthreads();
        }
        const int mybase = base_;
        if (p) cmp[mybase + v - 1] = (s << 11) | d;
        __syncthreads();
        if (tid == 0) base_ += scan_[255];
        __syncthreads();
    }
    if (tid == 0) count[tb] = base_;
}

// ---------------------------------------------------------------------------
// Fused MFMA step (projection folded in) + merged copy-through.
// 256-thread blocks (4 waves). Grid = COPYB + 8192.
// Step tiles: M=32 x N-quarter, acc[2][5]=40. Two-phase K-loop over ONE Ash:
//   phase 1: h_l|h_r (K=512, Bp, 16 slabs) via global_load_lds
//   restage: bf16 input rows (1KB each, one wave-load/row)
//   phase 2: x part (K=320, B2, 10 slabs)
// Biases added in the epilogue (4 scalar L2-hot loads). x_pack eliminated.
// ---------------------------------------------------------------------------
__global__ __launch_bounds__(256, 4) void step_kernel(
    const __hip_bfloat16* __restrict__ h_cur, const __hip_bfloat16* __restrict__ c_cur,
    __hip_bfloat16* __restrict__ h_next, __hip_bfloat16* __restrict__ c_next,
    const int* __restrict__ tree_ids_l, const int* __restrict__ tree_ids_r,
    const int* __restrict__ winner_t, const int* __restrict__ compact,
    const int* __restrict__ count, const __hip_bfloat16* __restrict__ inp,
    const float* __restrict__ b_iou, const float* __restrict__ b_f,
    const __hip_bfloat16* __restrict__ Bp, const __hip_bfloat16* __restrict__ B2,
    int t)
{
    const int tid = threadIdx.x;

    if (blockIdx.x < COPYB) {
        // ---- copy path: BS*32 uint4 chunks, grid-stride x8 ----
        const uint4* h_cur4 = (const uint4*)h_cur;
        const uint4* c_cur4 = (const uint4*)c_cur;
        uint4* h_next4 = (uint4*)h_next;
        uint4* c_next4 = (uint4*)c_next;
#pragma unroll
        for (int i = 0; i < 8; ++i) {
            const int idx = blockIdx.x * 256 + tid + i * (COPYB * 256);
            const int row = idx >> 5;
            const int d = row & (S_ - 1);
            if (d == 0) {
                const uint4 z = make_uint4(0u, 0u, 0u, 0u);
                h_next4[idx] = z;
                c_next4[idx] = z;
            } else if (winner_t[row] < 0) {
                h_next4[idx] = h_cur4[idx];
                c_next4[idx] = c_cur4[idx];
            }
        }
        return;
    }

    // ---- step path ----
    const int sb     = blockIdx.x - COPYB;       // 0..8191
    const int grp    = sb >> 5;                  // 0..255
    const int l32    = sb & 31;
    const int nq     = l32 >> 3;                 // N-quarter 0..3
    const int tile_g = grp * 8 + (l32 & 7);      // 0..2047
    const int b    = tile_g >> 6;
    const int tile = tile_g & 63;
    const int nAct = count[t * B_ + b];
    const int s0 = tile * 32;
    if (s0 >= nAct) return;

    __shared__ __hip_bfloat16 Ash[32][520];      // 32 x (512+8 pad) = 33.3 KB
    __shared__ int sS[32], sD[32], sIdl[32], sIdr[32];

    const int* cmp = compact + ((size_t)(t * B_ + b)) * S_;
    if (tid < 32) {
        const int gi = s0 + tid;
        const int pair = (gi < nAct) ? cmp[gi] : 0;   // 0 -> s=0,d=0 (inactive)
        sS[tid] = pair >> 11;
        sD[tid] = pair & 2047;
    }
    __syncthreads();

    const int lane = tid & 63;
    const int wave = tid >> 6;                   // 0..3
    const int m16 = lane & 15;
    const int q = lane >> 4;
    const int w16 = nq * 4 + wave;               // col-group 0..15
    const int cg = w16 * 16 + m16;               // h-col 0..255

    // Biases (L2-hot after first blocks)
    const float bi0 = b_iou[cg];
    const float bi1 = b_iou[256 + cg];
    const float bi2 = b_iou[512 + cg];
    const float bfv = b_f[cg];

    const int* idl_b = tree_ids_l + ((size_t)b * STEPS_ + t) * S_;
    const int* idr_b = tree_ids_r + ((size_t)b * STEPS_ + t) * S_;
    if (tid < 32)       sIdl[tid]      = idl_b[sS[tid]];
    else if (tid < 64)  sIdr[tid - 32] = idr_b[sS[tid - 32]];
    __syncthreads();

    // Issue c_l/c_r loads (raw bf16 bits); consumed in the epilogue.
    unsigned short clb[2][4], crb[2][4];
    const __hip_bfloat16* cbase = c_cur + (size_t)(b * S_) * H_ + cg;
#pragma unroll
    for (int sm = 0; sm < 2; ++sm)
#pragma unroll
        for (int j = 0; j < 4; ++j) {
            const int r = sm * 16 + q * 4 + j;
            clb[sm][j] = *(const unsigned short*)(cbase + (size_t)sIdl[r] * H_);
            crb[sm][j] = *(const unsigned short*)(cbase + (size_t)sIdr[r] * H_);
        }

    // Phase-1 staging via global_load_lds: wave w stages rows w, w+4, ..,w+28.
    {
        const int half = lane >> 5;
        const int c16 = lane & 31;
#pragma unroll
        for (int it = 0; it < 8; ++it) {
            const int r = wave + it * 4;
            const int src = half ? sIdr[r] : sIdl[r];
            const __hip_bfloat16* g =
                h_cur + ((size_t)(b * S_) + src) * H_ + c16 * 8;
            gload_lds16(g, &Ash[r][0]);
        }
    }
    __syncthreads();

    f32x4 acc[2][5];
    const f32x4 z4 = {0.f, 0.f, 0.f, 0.f};
#pragma unroll
    for (int sm = 0; sm < 2; ++sm)
#pragma unroll
        for (int g = 0; g < 5; ++g) acc[sm][g] = z4;

    const __hip_bfloat16* bp_base =
        Bp + ((size_t)(w16 * 80 + m16)) * 32 + q * 8;

    for (int ks = 0; ks < KSL; ++ks) {
        const bf16x8 a0 = *reinterpret_cast<const bf16x8*>(&Ash[m16][ks * 32 + q * 8]);
        const bf16x8 a1 = *reinterpret_cast<const bf16x8*>(&Ash[16 + m16][ks * 32 + q * 8]);
        const __hip_bfloat16* bk = bp_base + (size_t)ks * (NPACK * 32);
        bf16x8 bfrag[5];
#pragma unroll
        for (int g = 0; g < 5; ++g)
            bfrag[g] = *reinterpret_cast<const bf16x8*>(bk + g * 512);
#pragma unroll
        for (int g = 0; g < 5; ++g) {
            acc[0][g] = __builtin_amdgcn_mfma_f32_16x16x32_bf16(a0, bfrag[g], acc[0][g], 0, 0, 0);
            acc[1][g] = __builtin_amdgcn_mfma_f32_16x16x32_bf16(a1, bfrag[g], acc[1][g], 0, 0, 0);
        }
    }
    __syncthreads();                             // all waves done reading Ash

    // Restage Ash with bf16 input rows: 1KB/row = one full wave-load.
    {
#pragma unroll
        for (int it = 0; it < 8; ++it) {
            const int r = wave + it * 4;
            const __hip_bfloat16* g =
                inp + ((size_t)(b * S_) + sS[r]) * 512 + lane * 8;
            gload_lds16(g, &Ash[r][0]);
        }
    }
    __syncthreads();

    const __hip_bfloat16* b2_base =
        B2 + ((size_t)(w16 * 80 + m16)) * 32 + q * 8;

    for (int ks = 0; ks < KSL2; ++ks) {
        const bf16x8 a0 = *reinterpret_cast<const bf16x8*>(&Ash[m16][ks * 32 + q * 8]);
        const bf16x8 a1 = *reinterpret_cast<const bf16x8*>(&Ash[16 + m16][ks * 32 + q * 8]);
        const __hip_bfloat16* bk = b2_base + (size_t)ks * (NPACK * 32);
        bf16x8 bfrag[5];
#pragma unroll
        for (int g = 0; g < 5; ++g)
            bfrag[g] = *reinterpret_cast<const bf16x8*>(bk + g * 512);
#pragma unroll
        for (int g = 0; g < 5; ++g) {
            acc[0][g] = __builtin_amdgcn_mfma_f32_16x16x32_bf16(a0, bfrag[g], acc[0][g], 0, 0, 0);
            acc[1][g] = __builtin_amdgcn_mfma_f32_16x16x32_bf16(a1, bfrag[g], acc[1][g], 0, 0, 0);
        }
    }

    // Epilogue: pure register math + stores
#pragma unroll
    for (int sm = 0; sm < 2; ++sm) {
#pragma unroll
        for (int j = 0; j < 4; ++j) {
            const int r = sm * 16 + q * 4 + j;    // local row
            const int d = sD[r];
            if (d == 0) continue;
            const size_t orow = ((size_t)(b * S_ + d)) * H_;
            const float ig = sigm(acc[0][0][j * 0 + 0] * 0.f + acc[sm][0][j] + bi0);
            const float og = sigm(acc[sm][1][j] + bi1);
            const float ug = fast_tanh(acc[sm][2][j] + bi2);
            const float fl = sigm(acc[sm][3][j] + bfv);
            const float fr = sigm(acc[sm][4][j] + bfv);
            const float cl = bf16bits2f(clb[sm][j]);
            const float cr = bf16bits2f(crb[sm][j]);
            const float cn = ig * ug + fl * cl + fr * cr;
            const float hn = og * fast_tanh(cn);
            c_next[orow + cg] = __float2bfloat16(cn);
            h_next[orow + cg] = __float2bfloat16(hn);
        }
    }
}

// ---------------------------------------------------------------------------
// Final h,c bf16 -> fp32 into d_out
// ---------------------------------------------------------------------------
__global__ __launch_bounds__(256) void convert_kernel(
    const __hip_bfloat16* __restrict__ h, const __hip_bfloat16* __restrict__ c,
    float* __restrict__ out_h, float* __restrict__ out_c)
{
    const size_t i = ((size_t)blockIdx.x * 256 + threadIdx.x) * 8;
#pragma unroll
    for (int j = 0; j < 8; ++j) {
        out_h[i + j] = __bfloat162float(h[i + j]);
        out_c[i + j] = __bfloat162float(c[i + j]);
    }
}

// ---------------------------------------------------------------------------
// Root: roots[b] = max_s tree_ids[b, STEPS-1, s]; h_root = h[b, root]
// ---------------------------------------------------------------------------
__global__ __launch_bounds__(256) void root_kernel(
    const int* __restrict__ tree_ids,
    const __hip_bfloat16* __restrict__ h, float* __restrict__ h_root)
{
    const int b = blockIdx.x;
    const int tid = threadIdx.x;
    const int* ids = tree_ids + ((size_t)b * STEPS_ + (STEPS_ - 1)) * S_;
    __shared__ int red[256];
    int m = 0;
    for (int s = tid; s < S_; s += 256) m = max(m, ids[s]);
    red[tid] = m;
    __syncthreads();
    for (int off = 128; off > 0; off >>= 1) {
        if (tid < off) red[tid] = max(red[tid], red[tid + off]);
        __syncthreads();
    }
    const int root = red[0];
    h_root[(size_t)b * H_ + tid] =
        __bfloat162float(h[((size_t)(b * S_) + root) * H_ + tid]);
}

// ---------------------------------------------------------------------------
extern "C" void kernel_launch(void* const* d_in, const int* in_sizes, int n_in,
                              void* d_out, int out_size, void* d_ws, size_t ws_size,
                              hipStream_t stream)
{
    const float* input_ids  = (const float*)d_in[0];
    const int*   tree_ids   = (const int*)d_in[1];
    const int*   tree_ids_r = (const int*)d_in[2];
    const int*   tree_ids_l = (const int*)d_in[3];
    const float* W_iou   = (const float*)d_in[4];
    const float* b_iou   = (const float*)d_in[5];
    const float* U_iou_l = (const float*)d_in[6];
    const float* U_iou_r = (const float*)d_in[7];
    const float* W_f     = (const float*)d_in[8];
    const float* b_f     = (const float*)d_in[9];
    const float* U_f_ll  = (const float*)d_in[10];
    const float* U_f_lr  = (const float*)d_in[11];
    const float* U_f_rl  = (const float*)d_in[12];
    const float* U_f_rr  = (const float*)d_in[13];

    float* out = (float*)d_out;
    float* out_h = out;
    float* out_c = out + (size_t)BS_ * H_;
    float* out_root = out + (size_t)2 * BS_ * H_;

    // ws layout (bytes):
    //   inp_bf16 bf16 [BS][512]  : 0          .. 67108864
    //   B2       bf16 [10][1280][32]: 67108864 .. 67928064
    //   hA     bf16 [BS][256]    : 134217728  .. 167772160
    //   cA     bf16 [BS][256]    : 167772160  .. 201326592
    //   winner int  [24][B][S]   : 201326592  .. 207618048
    //   Bp     bf16 [16][1280][32]: 207618048 .. 208928768
    char* ws = (char*)d_ws;
    __hip_bfloat16* inp_bf = (__hip_bfloat16*)(ws);
    __hip_bfloat16* B2     = (__hip_bfloat16*)(ws + 67108864ull);
    __hip_bfloat16* hA     = (__hip_bfloat16*)(ws + 134217728ull);
    __hip_bfloat16* cA     = (__hip_bfloat16*)(ws + 167772160ull);
    int*            winner = (int*)(ws + 201326592ull);
    __hip_bfloat16* Bp     = (__hip_bfloat16*)(ws + 207618048ull);
    // Ping-pong partners live in d_out's h/c regions (fp32-sized, so roomy):
    // bf16 ping-pong uses the lower 32 MB of each 64 MB fp32 region.
    __hip_bfloat16* hB     = (__hip_bfloat16*)out_h;
    __hip_bfloat16* cB     = (__hip_bfloat16*)out_c;
    // Compact lists live in the unused upper 32 MB of the out_h region;
    // convert_kernel overwrites them only at the very end.
    int* compact = (int*)((char*)out_h + 33554432ull);   // 24*32*2048*4 = 6.29MB
    int* cnt     = compact + (size_t)STEPS_ * B_ * S_;   // 768 ints

    hipMemsetAsync(hA, 0, (size_t)BS_ * H_ * sizeof(__hip_bfloat16), stream);
    hipMemsetAsync(cA, 0, (size_t)BS_ * H_ * sizeof(__hip_bfloat16), stream);
    hipMemsetAsync(winner, 0xFF, (size_t)STEPS_ * BS_ * sizeof(int), stream);

    pack_B_kernel<<<(KSL * NPACK * 32 + 255) / 256, 256, 0, stream>>>(
        U_iou_l, U_iou_r, U_f_ll, U_f_lr, U_f_rl, U_f_rr, Bp);
    pack_B2_kernel<<<(KSL2 * NPACK * 32 + 255) / 256, 256, 0, stream>>>(
        W_iou, W_f, B2);
    winner_kernel<<<(B_ * STEPS_ * S_) / 256, 256, 0, stream>>>(tree_ids, winner);
    compact_kernel<<<STEPS_ * B_, 256, 0, stream>>>(winner, compact, cnt);
    inpcvt_kernel<<<(BS_ * 64) / 256, 256, 0, stream>>>(input_ids, inp_bf);

    for (int t = 0; t < STEPS_; ++t) {
        const __hip_bfloat16* hc = (t & 1) ? hB : hA;
        const __hip_bfloat16* cc = (t & 1) ? cB : cA;
        __hip_bfloat16*       hn = (t & 1) ? hA : hB;
        __hip_bfloat16*       cn = (t & 1) ? cA : cB;
        const int* wt = winner + (size_t)t * BS_;

        step_kernel<<<COPYB + B_ * 64 * 4, 256, 0, stream>>>(
            hc, cc, hn, cn, tree_ids_l, tree_ids_r, wt,
            compact, cnt, inp_bf, b_iou, b_f, Bp, B2, t);
    }

    // t=23 (odd) wrote hA/cA: convert to fp32 into d_out
    convert_kernel<<<(BS_ * H_ / 8) / 256, 256, 0, stream>>>(hA, cA, out_h, out_c);
    root_kernel<<<B_, 256, 0, stream>>>(tree_ids, hA, out_root);
}

// Round 17
// 4226.364 us; speedup vs baseline: 1.3619x; 1.3619x over previous
//
#include <hip/hip_runtime.h>
#include <hip/hip_bf16.h>
#include <math.h>

// Problem constants
#define B_     32
#define S_     2048
#define E_     300
#define H_     256
#define STEPS_ 24
#define BS_    (B_ * S_)      // 65536
#define NPACK  1280           // 5 gates * 256
#define KSL    16             // 512/32 k-slabs
#define KSLP   10             // 320/32 (proj K padded)

typedef __bf16 bf16x8 __attribute__((ext_vector_type(8)));
typedef float  f32x4  __attribute__((ext_vector_type(4)));

__device__ __forceinline__ float sigm(float x) {
    return 1.0f / (1.0f + __expf(-x));
}
__device__ __forceinline__ float fast_tanh(float x) {
    return 2.0f * sigm(2.0f * x) - 1.0f;
}
__device__ __forceinline__ float bf16bits2f(unsigned short u) {
    return __uint_as_float(((unsigned)u) << 16);
}
// Async global->LDS, 16B/lane. LDS dest = wave-uniform base + lane*16;
// global src is per-lane. (m03/m97/m104 semantics.)
__device__ __forceinline__ void gload_lds16(const void* g, void* l) {
    __builtin_amdgcn_global_load_lds(
        (const __attribute__((address_space(1))) void*)g,
        (__attribute__((address_space(3))) void*)l, 16, 0, 0);
}

// ---------------------------------------------------------------------------
// Pack step-GEMM B: Bp[ks][p][kin], p = w*80 + g*16 + c_lo, col c = w*16+c_lo.
// k<256 -> U_*_l[k], k>=256 -> U_*_r[k-256]. Gates: 0=i,1=o,2=u,3=f_l,4=f_r.
// ---------------------------------------------------------------------------
__global__ __launch_bounds__(256) void pack_B_kernel(
    const float* __restrict__ U_iou_l, const float* __restrict__ U_iou_r,
    const float* __restrict__ U_f_ll,  const float* __restrict__ U_f_lr,
    const float* __restrict__ U_f_rl,  const float* __restrict__ U_f_rr,
    __hip_bfloat16* __restrict__ Bp)
{
    const int idx = blockIdx.x * 256 + threadIdx.x;      // 16*1280*32 = 655360
    if (idx >= KSL * NPACK * 32) return;
    const int ks = idx / (NPACK * 32);
    const int rem = idx - ks * (NPACK * 32);
    const int p = rem >> 5;
    const int kin = rem & 31;
    const int k = ks * 32 + kin;
    const int w = p / 80;
    const int rg = p - w * 80;
    const int g = rg >> 4;
    const int c = w * 16 + (rg & 15);
    float v;
    if (g < 3) {
        const int col = g * 256 + c;
        v = (k < 256) ? U_iou_l[k * 768 + col] : U_iou_r[(k - 256) * 768 + col];
    } else if (g == 3) {
        v = (k < 256) ? U_f_ll[k * 256 + c] : U_f_lr[(k - 256) * 256 + c];
    } else {
        v = (k < 256) ? U_f_rl[k * 256 + c] : U_f_rr[(k - 256) * 256 + c];
    }
    Bp[idx] = __float2bfloat16(v);
}

// ---------------------------------------------------------------------------
// Pack projection weights for gate-interleaved output:
// Wp[ks][p][kin]; p = cw*64 + g*16 + c_lo; col = cw*16+c_lo;
// g in {0=i,1=o,2=u,3=f}. k>=300 zero-padded.
// ---------------------------------------------------------------------------
__global__ __launch_bounds__(256) void pack_W_kernel(
    const float* __restrict__ W_iou, const float* __restrict__ W_f,
    __hip_bfloat16* __restrict__ Wp)
{
    const int idx = blockIdx.x * 256 + threadIdx.x;      // 10*1024*32 = 327680
    if (idx >= KSLP * 1024 * 32) return;
    const int ks = idx / (1024 * 32);
    const int rem = idx - ks * (1024 * 32);
    const int p = rem >> 5;
    const int kin = rem & 31;
    const int k = ks * 32 + kin;
    const int cw = p >> 6;
    const int g = (p >> 4) & 3;
    const int col = cw * 16 + (p & 15);
    float v = 0.f;
    if (k < E_) v = (g < 3) ? W_iou[k * 768 + g * 256 + col] : W_f[k * 256 + col];
    Wp[idx] = __float2bfloat16(v);
}

// ---------------------------------------------------------------------------
// Winner: winner[t][b][d] = max s with tree_ids[b][t][s]==d (last-wins scatter)
// ---------------------------------------------------------------------------
__global__ __launch_bounds__(256) void winner_kernel(
    const int* __restrict__ tree_ids, int* __restrict__ winner)
{
    const int idx = blockIdx.x * 256 + threadIdx.x;
    if (idx >= B_ * STEPS_ * S_) return;
    const int b = idx / (STEPS_ * S_);
    const int rem = idx - b * (STEPS_ * S_);
    const int t = rem / S_;
    const int s = rem - t * S_;
    const int d = tree_ids[idx];
    if ((unsigned)d < (unsigned)S_)
        atomicMax(&winner[(size_t)t * BS_ + b * S_ + d], s);
}

// ---------------------------------------------------------------------------
// Epoch: ep[row] bit t = buffer index holding row's value at START of step t.
// bit STEPS_ = final buffer. Row flips buffer each step it wins (d!=0).
// ---------------------------------------------------------------------------
__global__ __launch_bounds__(256) void epoch_kernel(
    const int* __restrict__ winner, unsigned* __restrict__ ep)
{
    const int r = blockIdx.x * 256 + threadIdx.x;        // 0..BS-1
    if (r >= BS_) return;
    const int d = r & (S_ - 1);
    unsigned bits = 0;
    int e = 0;
    for (int t = 0; t < STEPS_; ++t) {
        bits |= (unsigned)e << t;
        if (d != 0 && winner[(size_t)t * BS_ + r] >= 0) e ^= 1;
    }
    bits |= (unsigned)e << STEPS_;
    ep[r] = bits;
}

// ---------------------------------------------------------------------------
// Augment child index tables with their read-buffer bit (bit 11):
// aug[idx] = child_row | (ep[child]>>t & 1) << 11.  Layout [B][STEPS][S].
// ---------------------------------------------------------------------------
__global__ __launch_bounds__(256) void aug_kernel(
    const int* __restrict__ tree_ids_l, const int* __restrict__ tree_ids_r,
    const unsigned* __restrict__ ep,
    int* __restrict__ aug_l, int* __restrict__ aug_r)
{
    const int idx = blockIdx.x * 256 + threadIdx.x;
    if (idx >= B_ * STEPS_ * S_) return;
    const int b = idx / (STEPS_ * S_);
    const int rem = idx - b * (STEPS_ * S_);
    const int t = rem / S_;
    const int vl = tree_ids_l[idx];
    const int vr = tree_ids_r[idx];
    const int bl = (ep[b * S_ + vl] >> t) & 1;
    const int br = (ep[b * S_ + vr] >> t) & 1;
    aug_l[idx] = vl | (bl << 11);
    aug_r[idx] = vr | (br << 11);
}

// ---------------------------------------------------------------------------
// Compaction: per (t,b), ordered list of active (s,d) pairs (d!=0, winner>=0),
// packed as (s<<11)|d | (write_buffer<<22). One block per (t,b).
// ---------------------------------------------------------------------------
__global__ __launch_bounds__(256) void compact_kernel(
    const int* __restrict__ winner, const unsigned* __restrict__ ep,
    int* __restrict__ compact, int* __restrict__ count)
{
    const int tb = blockIdx.x;               // t*32 + b ; winner row = tb*S_
    const int t_ = tb / B_;
    const int b_ = tb - t_ * B_;
    const int tid = threadIdx.x;
    const int* w = winner + (size_t)tb * S_;
    int* cmp = compact + (size_t)tb * S_;
    __shared__ int scan_[256];
    __shared__ int base_;
    if (tid == 0) base_ = 0;
    __syncthreads();
    for (int chunk = 0; chunk < S_ / 256; ++chunk) {
        const int d = chunk * 256 + tid;
        const int s = w[d];
        const int p = (d != 0 && s >= 0) ? 1 : 0;
        int v = p;
        scan_[tid] = v;
        __syncthreads();
        for (int off = 1; off < 256; off <<= 1) {
            const int add = (tid >= off) ? scan_[tid - off] : 0;
            __syncthreads();
            v += add;
            scan_[tid] = v;
            __syncthreads();
        }
        const int mybase = base_;
        if (p) {
            const int wb = (ep[b_ * S_ + d] >> (t_ + 1)) & 1;
            cmp[mybase + v - 1] = (s << 11) | d | (wb << 22);
        }
        __syncthreads();
        if (tid == 0) base_ += scan_[255];
        __syncthreads();
    }
    if (tid == 0) count[tb] = base_;
}

// ---------------------------------------------------------------------------
// Projection GEMM (MFMA), M=64 B-reuse variant. Block: 256 thr (4 waves),
// 64 rows x 64 packed-col group (one col-block of 4). Wave w owns ONE
// 16-col chunk (cb*4+w) x 4 gates x 4 row-slabs: acc[4][4] = 64 f32.
// ---------------------------------------------------------------------------
__global__ __launch_bounds__(256, 3) void proj_kernel(
    const float* __restrict__ input, const __hip_bfloat16* __restrict__ Wp,
    const float* __restrict__ b_iou, const float* __restrict__ b_f,
    __hip_bfloat16* __restrict__ x_pack)
{
    __shared__ __hip_bfloat16 Ash[64][328];              // 64 x (320+8 pad) = 42 KB
    const int tid = threadIdx.x;
    // Decode: group of 32 blocks = 8 row-groups x 4 col-blocks (stride 8)
    const int grp = blockIdx.x >> 5;                     // 0..127
    const int l32 = blockIdx.x & 31;
    const int cb  = l32 >> 3;                            // col-block 0..3
    const int rg  = grp * 8 + (l32 & 7);                 // row-group 0..1023
    const int row0 = rg * 64;

    // Stage A: fp32 -> bf16, 64 rows x 320 (zeros past 300); 20 iters
    for (int it = 0; it < 20; ++it) {
        const int idx = tid + it * 256;                  // 64 rows * 80 chunks
        const int r = idx / 80;
        const int c4 = idx - r * 80;
        float4 v = make_float4(0.f, 0.f, 0.f, 0.f);
        if (c4 < 75) v = *(const float4*)(input + (size_t)(row0 + r) * E_ + c4 * 4);
        union { __hip_bfloat16 h[4]; uint2 u; } tconv;
        tconv.h[0] = __float2bfloat16(v.x);
        tconv.h[1] = __float2bfloat16(v.y);
        tconv.h[2] = __float2bfloat16(v.z);
        tconv.h[3] = __float2bfloat16(v.w);
        *(uint2*)&Ash[r][c4 * 4] = tconv.u;
    }
    __syncthreads();

    const int lane = tid & 63;
    const int wave = tid >> 6;
    const int m16 = lane & 15;
    const int q = lane >> 4;
    const int chunk = cb * 4 + wave;                     // 16-col group 0..15
    const int c = chunk * 16 + m16;                      // h-col 0..255

    f32x4 acc[4][4];                                     // [slab][gate]
    const f32x4 z4 = {0.f, 0.f, 0.f, 0.f};
#pragma unroll
    for (int s = 0; s < 4; ++s)
#pragma unroll
        for (int g = 0; g < 4; ++g) acc[s][g] = z4;

    // p = chunk*64 + g*16 + m16
    const __hip_bfloat16* wpb = Wp + ((size_t)(chunk * 64 + m16)) * 32 + q * 8;
    for (int ks = 0; ks < KSLP; ++ks) {
        bf16x8 bfrag[4];
#pragma unroll
        for (int g = 0; g < 4; ++g)
            bfrag[g] = *reinterpret_cast<const bf16x8*>(wpb + (size_t)ks * 32768 + g * 512);
        bf16x8 a[4];
#pragma unroll
        for (int s = 0; s < 4; ++s)
            a[s] = *reinterpret_cast<const bf16x8*>(&Ash[s * 16 + m16][ks * 32 + q * 8]);
#pragma unroll
        for (int s = 0; s < 4; ++s)
#pragma unroll
            for (int g = 0; g < 4; ++g)
                acc[s][g] = __builtin_amdgcn_mfma_f32_16x16x32_bf16(a[s], bfrag[g], acc[s][g], 0, 0, 0);
    }

    // Epilogue: 4 gates per (row, col) in this thread -> one uint2 store
    const float bi0 = b_iou[c];
    const float bi1 = b_iou[256 + c];
    const float bi2 = b_iou[512 + c];
    const float bf_ = b_f[c];
#pragma unroll
    for (int s = 0; s < 4; ++s) {
#pragma unroll
        for (int j = 0; j < 4; ++j) {
            const int row = row0 + s * 16 + q * 4 + j;
            const size_t xrow = (size_t)row * 1024;
            union { __hip_bfloat16 h[4]; uint2 u; } pk;
            pk.h[0] = __float2bfloat16(acc[s][0][j] + bi0);
            pk.h[1] = __float2bfloat16(acc[s][1][j] + bi1);
            pk.h[2] = __float2bfloat16(acc[s][2][j] + bi2);
            pk.h[3] = __float2bfloat16(acc[s][3][j] + bf_);
            *(uint2*)(x_pack + xrow + (size_t)c * 4) = pk.u;
        }
    }
}

// ---------------------------------------------------------------------------
// Fused MFMA step, dual-buffer epoch scheme — NO copy pass. 256 thr (4 waves),
// grid 8192. M=32 x N-quarter tiles, acc[2][5]=40. Children read from
// buf[bit11 of aug]; winners write buf[bit22 of compact]. Non-winner rows
// keep their value in place (epoch tracks which buffer) — the 48 MB/step
// carry-through copy is eliminated. h0/c0 and h1/c1 are both read AND
// written (buffer selection per row), hence non-const.
// ---------------------------------------------------------------------------
__global__ __launch_bounds__(256, 4) void step_kernel(
    __hip_bfloat16* __restrict__ h0, __hip_bfloat16* __restrict__ c0,
    __hip_bfloat16* __restrict__ h1, __hip_bfloat16* __restrict__ c1,
    const int* __restrict__ aug_l, const int* __restrict__ aug_r,
    const int* __restrict__ compact, const int* __restrict__ count,
    const __hip_bfloat16* __restrict__ x_pack,
    const __hip_bfloat16* __restrict__ Bp, int t)
{
    const int tid = threadIdx.x;
    const int sb     = blockIdx.x;               // 0..8191
    const int grp    = sb >> 5;                  // 0..255
    const int l32    = sb & 31;
    const int nq     = l32 >> 3;                 // N-quarter 0..3
    const int tile_g = grp * 8 + (l32 & 7);      // 0..2047
    const int b    = tile_g >> 6;
    const int tile = tile_g & 63;
    const int nAct = count[t * B_ + b];
    const int s0 = tile * 32;
    if (s0 >= nAct) return;

    __shared__ __hip_bfloat16 Ash[32][520];      // 32 x (512+8 pad) = 33.3 KB
    __shared__ int sS[32], sD[32], sW[32], sIdl[32], sIdr[32];

    const int* cmp = compact + ((size_t)(t * B_ + b)) * S_;
    if (tid < 32) {
        const int gi = s0 + tid;
        const int pair = (gi < nAct) ? cmp[gi] : 0;   // 0 -> s=0,d=0 (inactive)
        sS[tid] = (pair >> 11) & 2047;
        sD[tid] = pair & 2047;
        sW[tid] = (pair >> 22) & 1;
    }
    __syncthreads();

    const int lane = tid & 63;
    const int wave = tid >> 6;                   // 0..3
    const int m16 = lane & 15;
    const int q = lane >> 4;
    const int w16 = nq * 4 + wave;               // col-group 0..15
    const int cg = w16 * 16 + m16;               // h-col 0..255

    // Issue x_pack loads now; consumed only in the epilogue.
    uint2 xv[2][4];
#pragma unroll
    for (int sm = 0; sm < 2; ++sm)
#pragma unroll
        for (int j = 0; j < 4; ++j) {
            const int r = sm * 16 + q * 4 + j;
            xv[sm][j] = *(const uint2*)(x_pack
                + ((size_t)(b * S_ + sS[r])) * 1024 + (size_t)cg * 4);
        }

    const int* idl_b = aug_l + ((size_t)b * STEPS_ + t) * S_;
    const int* idr_b = aug_r + ((size_t)b * STEPS_ + t) * S_;
    if (tid < 32)       sIdl[tid]      = idl_b[sS[tid]];
    else if (tid < 64)  sIdr[tid - 32] = idr_b[sS[tid - 32]];
    __syncthreads();

    // Issue c_l/c_r loads (raw bf16 bits, buffer-selected); epilogue-consumed.
    unsigned short clb[2][4], crb[2][4];
#pragma unroll
    for (int sm = 0; sm < 2; ++sm)
#pragma unroll
        for (int j = 0; j < 4; ++j) {
            const int r = sm * 16 + q * 4 + j;
            const int vl = sIdl[r];
            const int vr = sIdr[r];
            const __hip_bfloat16* cl_ = (vl >> 11) ? c1 : c0;
            const __hip_bfloat16* cr_ = (vr >> 11) ? c1 : c0;
            clb[sm][j] = *(const unsigned short*)(
                cl_ + ((size_t)(b * S_) + (vl & 2047)) * H_ + cg);
            crb[sm][j] = *(const unsigned short*)(
                cr_ + ((size_t)(b * S_) + (vr & 2047)) * H_ + cg);
        }

    // h staging via global_load_lds: wave w stages rows w, w+4, ..., w+28.
    // LDS dest = &Ash[r][0] + lane*16 (HW); global src per-lane + per-row buf.
    {
        const int half = lane >> 5;
        const int c16 = lane & 31;
#pragma unroll
        for (int it = 0; it < 8; ++it) {
            const int r = wave + it * 4;
            const int v = half ? sIdr[r] : sIdl[r];
            const __hip_bfloat16* hb = (v >> 11) ? h1 : h0;
            const __hip_bfloat16* g =
                hb + ((size_t)(b * S_) + (v & 2047)) * H_ + c16 * 8;
            gload_lds16(g, &Ash[r][0]);
        }
    }
    __syncthreads();

    f32x4 acc[2][5];
    const f32x4 z4 = {0.f, 0.f, 0.f, 0.f};
#pragma unroll
    for (int sm = 0; sm < 2; ++sm)
#pragma unroll
        for (int g = 0; g < 5; ++g) acc[sm][g] = z4;

    const __hip_bfloat16* bp_base =
        Bp + ((size_t)(w16 * 80 + m16)) * 32 + q * 8;

    for (int ks = 0; ks < KSL; ++ks) {
        const bf16x8 a0 = *reinterpret_cast<const bf16x8*>(&Ash[m16][ks * 32 + q * 8]);
        const bf16x8 a1 = *reinterpret_cast<const bf16x8*>(&Ash[16 + m16][ks * 32 + q * 8]);
        const __hip_bfloat16* bk = bp_base + (size_t)ks * (NPACK * 32);
        bf16x8 bfrag[5];
#pragma unroll
        for (int g = 0; g < 5; ++g)
            bfrag[g] = *reinterpret_cast<const bf16x8*>(bk + g * 512);
#pragma unroll
        for (int g = 0; g < 5; ++g) {
            acc[0][g] = __builtin_amdgcn_mfma_f32_16x16x32_bf16(a0, bfrag[g], acc[0][g], 0, 0, 0);
            acc[1][g] = __builtin_amdgcn_mfma_f32_16x16x32_bf16(a1, bfrag[g], acc[1][g], 0, 0, 0);
        }
    }

    // Epilogue: pure register math + buffer-selected stores
#pragma unroll
    for (int sm = 0; sm < 2; ++sm) {
#pragma unroll
        for (int j = 0; j < 4; ++j) {
            const int r = sm * 16 + q * 4 + j;    // local row
            const int d = sD[r];
            if (d == 0) continue;
            const size_t orow = ((size_t)(b * S_ + d)) * H_;
            union { uint2 u; unsigned short x[4]; } xu;
            xu.u = xv[sm][j];
            const float xi = bf16bits2f(xu.x[0]);
            const float xo = bf16bits2f(xu.x[1]);
            const float xuu = bf16bits2f(xu.x[2]);
            const float xf = bf16bits2f(xu.x[3]);
            const float ig = sigm(acc[sm][0][j] + xi);
            const float og = sigm(acc[sm][1][j] + xo);
            const float ug = fast_tanh(acc[sm][2][j] + xuu);
            const float fl = sigm(acc[sm][3][j] + xf);
            const float fr = sigm(acc[sm][4][j] + xf);
            const float cl = bf16bits2f(clb[sm][j]);
            const float cr = bf16bits2f(crb[sm][j]);
            const float cn = ig * ug + fl * cl + fr * cr;
            const float hn = og * fast_tanh(cn);
            __hip_bfloat16* hd = sW[r] ? h1 : h0;
            __hip_bfloat16* cd = sW[r] ? c1 : c0;
            cd[orow + cg] = __float2bfloat16(cn);
            hd[orow + cg] = __float2bfloat16(hn);
        }
    }
}

// ---------------------------------------------------------------------------
// Consolidate: rows whose final value sits in buffer 1 -> copy into buffer 0.
// idx over BS*32 uint4 chunks (16B of h and 16B of c per chunk).
// ---------------------------------------------------------------------------
__global__ __launch_bounds__(256) void consolidate_kernel(
    const unsigned* __restrict__ ep,
    const uint4* __restrict__ h1, uint4* __restrict__ h0,
    const uint4* __restrict__ c1, uint4* __restrict__ c0)
{
    const int idx = blockIdx.x * 256 + threadIdx.x;      // BS*32
    const int row = idx >> 5;
    if ((ep[row] >> STEPS_) & 1) {
        h0[idx] = h1[idx];
        c0[idx] = c1[idx];
    }
}

// ---------------------------------------------------------------------------
// Final h,c bf16 -> fp32 into d_out
// ---------------------------------------------------------------------------
__global__ __launch_bounds__(256) void convert_kernel(
    const __hip_bfloat16* __restrict__ h, const __hip_bfloat16* __restrict__ c,
    float* __restrict__ out_h, float* __restrict__ out_c)
{
    const size_t i = ((size_t)blockIdx.x * 256 + threadIdx.x) * 8;
#pragma unroll
    for (int j = 0; j < 8; ++j) {
        out_h[i + j] = __bfloat162float(h[i + j]);
        out_c[i + j] = __bfloat162float(c[i + j]);
    }
}

// ---------------------------------------------------------------------------
// Root: roots[b] = max_s tree_ids[b, STEPS-1, s]; h_root = h[b, root]
// ---------------------------------------------------------------------------
__global__ __launch_bounds__(256) void root_kernel(
    const int* __restrict__ tree_ids,
    const __hip_bfloat16* __restrict__ h, float* __restrict__ h_root)
{
    const int b = blockIdx.x;
    const int tid = threadIdx.x;
    const int* ids = tree_ids + ((size_t)b * STEPS_ + (STEPS_ - 1)) * S_;
    __shared__ int red[256];
    int m = 0;
    for (int s = tid; s < S_; s += 256) m = max(m, ids[s]);
    red[tid] = m;
    __syncthreads();
    for (int off = 128; off > 0; off >>= 1) {
        if (tid < off) red[tid] = max(red[tid], red[tid + off]);
        __syncthreads();
    }
    const int root = red[0];
    h_root[(size_t)b * H_ + tid] =
        __bfloat162float(h[((size_t)(b * S_) + root) * H_ + tid]);
}

// ---------------------------------------------------------------------------
extern "C" void kernel_launch(void* const* d_in, const int* in_sizes, int n_in,
                              void* d_out, int out_size, void* d_ws, size_t ws_size,
                              hipStream_t stream)
{
    const float* input_ids  = (const float*)d_in[0];
    const int*   tree_ids   = (const int*)d_in[1];
    const int*   tree_ids_r = (const int*)d_in[2];
    const int*   tree_ids_l = (const int*)d_in[3];
    const float* W_iou   = (const float*)d_in[4];
    const float* b_iou   = (const float*)d_in[5];
    const float* U_iou_l = (const float*)d_in[6];
    const float* U_iou_r = (const float*)d_in[7];
    const float* W_f     = (const float*)d_in[8];
    const float* b_f     = (const float*)d_in[9];
    const float* U_f_ll  = (const float*)d_in[10];
    const float* U_f_lr  = (const float*)d_in[11];
    const float* U_f_rl  = (const float*)d_in[12];
    const float* U_f_rr  = (const float*)d_in[13];

    float* out = (float*)d_out;
    float* out_h = out;
    float* out_c = out + (size_t)BS_ * H_;
    float* out_root = out + (size_t)2 * BS_ * H_;

    // ws layout (bytes):
    //   x_pack bf16 [BS][1024]   : 0          .. 134217728
    //   hA     bf16 [BS][256]    : 134217728  .. 167772160
    //   cA     bf16 [BS][256]    : 167772160  .. 201326592
    //   winner int  [24][B][S]   : 201326592  .. 207618048
    //   Bp     bf16 [16][1280][32]: 207618048 .. 208928768
    //   Wp     bf16 [10][1024][32]: 208928768 .. 209584128
    char* ws = (char*)d_ws;
    __hip_bfloat16* x_pack = (__hip_bfloat16*)(ws);
    __hip_bfloat16* hA     = (__hip_bfloat16*)(ws + 134217728ull);
    __hip_bfloat16* cA     = (__hip_bfloat16*)(ws + 167772160ull);
    int*            winner = (int*)(ws + 201326592ull);
    __hip_bfloat16* Bp     = (__hip_bfloat16*)(ws + 207618048ull);
    __hip_bfloat16* Wp     = (__hip_bfloat16*)(ws + 208928768ull);
    // Buffer-1 (hB/cB) lives in d_out's h/c regions (lower 32 MB of each).
    __hip_bfloat16* hB     = (__hip_bfloat16*)out_h;
    __hip_bfloat16* cB     = (__hip_bfloat16*)out_c;
    // Compact lists: upper 32 MB of out_h (dead until final convert).
    int* compact = (int*)((char*)out_h + 33554432ull);   // 24*32*2048*4 = 6.29MB
    int* cnt     = compact + (size_t)STEPS_ * B_ * S_;   // 768 ints
    // Epoch + augmented child tables: upper 32 MB of out_c.
    int* aug_l   = (int*)((char*)out_c + 33554432ull);   // 6.29 MB
    int* aug_r   = aug_l + (size_t)B_ * STEPS_ * S_;     // 6.29 MB
    unsigned* ep = (unsigned*)(aug_r + (size_t)B_ * STEPS_ * S_); // 256 KB

    hipMemsetAsync(hA, 0, (size_t)BS_ * H_ * sizeof(__hip_bfloat16), stream);
    hipMemsetAsync(cA, 0, (size_t)BS_ * H_ * sizeof(__hip_bfloat16), stream);
    hipMemsetAsync(winner, 0xFF, (size_t)STEPS_ * BS_ * sizeof(int), stream);

    pack_B_kernel<<<(KSL * NPACK * 32 + 255) / 256, 256, 0, stream>>>(
        U_iou_l, U_iou_r, U_f_ll, U_f_lr, U_f_rl, U_f_rr, Bp);
    pack_W_kernel<<<(KSLP * 1024 * 32 + 255) / 256, 256, 0, stream>>>(W_iou, W_f, Wp);
    winner_kernel<<<(B_ * STEPS_ * S_) / 256, 256, 0, stream>>>(tree_ids, winner);
    epoch_kernel<<<BS_ / 256, 256, 0, stream>>>(winner, ep);
    compact_kernel<<<STEPS_ * B_, 256, 0, stream>>>(winner, ep, compact, cnt);
    aug_kernel<<<(B_ * STEPS_ * S_) / 256, 256, 0, stream>>>(
        tree_ids_l, tree_ids_r, ep, aug_l, aug_r);
    proj_kernel<<<(BS_ / 64) * 4, 256, 0, stream>>>(input_ids, Wp, b_iou, b_f, x_pack);

    for (int t = 0; t < STEPS_; ++t) {
        step_kernel<<<B_ * 64 * 4, 256, 0, stream>>>(
            hA, cA, hB, cB, aug_l, aug_r, compact, cnt, x_pack, Bp, t);
    }

    // Move buffer-1-resident rows into buffer 0, then emit fp32 outputs.
    consolidate_kernel<<<(BS_ * 32) / 256, 256, 0, stream>>>(
        ep, (const uint4*)hB, (uint4*)hA, (const uint4*)cB, (uint4*)cA);
    convert_kernel<<<(BS_ * H_ / 8) / 256, 256, 0, stream>>>(hA, cA, out_h, out_c);
    root_kernel<<<B_, 256, 0, stream>>>(tree_ids, hA, out_root);
}